// Round 1
// baseline (1916.346 us; speedup 1.0000x reference)
//
#include <hip/hip_runtime.h>
#include <math.h>

#define DM 768
#define DI 1536
#define NS 16
#define LL 2048
#define MROWS 4096

__device__ __forceinline__ float4 ld4(const float* p) { return *(const float4*)p; }

// ---------------- RMSNorm ----------------
__global__ __launch_bounds__(256) void rmsnorm_kernel(const float* __restrict__ x,
                                                      const float* __restrict__ w,
                                                      float* __restrict__ xn) {
  int row = blockIdx.x;
  const float* xr = x + (size_t)row * DM;
  float* xo = xn + (size_t)row * DM;
  int tid = threadIdx.x;
  float v0 = xr[tid], v1 = xr[tid + 256], v2 = xr[tid + 512];
  float ss = v0 * v0 + v1 * v1 + v2 * v2;
#pragma unroll
  for (int o = 32; o > 0; o >>= 1) ss += __shfl_xor(ss, o, 64);
  __shared__ float red[4];
  if ((tid & 63) == 0) red[tid >> 6] = ss;
  __syncthreads();
  float tot = red[0] + red[1] + red[2] + red[3];
  float sc = rsqrtf(tot * (1.0f / 768.0f) + 1.1920928955078125e-07f);
  xo[tid] = v0 * sc * w[tid];
  xo[tid + 256] = v1 * sc * w[tid + 256];
  xo[tid + 512] = v2 * sc * w[tid + 512];
}

// ---------------- Generic fp32 NT-GEMM: C = act(A@B^T + bias) (+resid) ----------------
// A: M x K (lda), Bw: N x K (ldb), C: M x N (ldc). resid uses ldc.
template <int ACT, bool BIAS, bool RESID>
__global__ __launch_bounds__(256) void gemm_nt(const float* __restrict__ A,
                                               const float* __restrict__ Bw,
                                               const float* __restrict__ bias,
                                               const float* __restrict__ resid,
                                               float* __restrict__ C, int M, int N,
                                               int K, int lda, int ldb, int ldc) {
  constexpr int BK = 16;
  __shared__ float As[BK][68];  // 68: +4 pad keeps 16B alignment for float4 reads
  __shared__ float Bs[BK][68];
  int tid = threadIdx.x;
  int bm = blockIdx.y * 64, bn = blockIdx.x * 64;
  int lr = tid >> 2;          // 0..63
  int lk = (tid & 3) << 2;    // 0,4,8,12
  int r0 = (tid >> 4) << 2;   // 0..60
  int c0 = (tid & 15) << 2;   // 0..60
  float acc[4][4] = {};
  const float* Ap = A + (size_t)(bm + lr) * lda + lk;
  const float* Bp = Bw + (size_t)(bn + lr) * ldb + lk;
  bool aok = (bm + lr) < M;
  bool bok = (bn + lr) < N;
  for (int k0 = 0; k0 < K; k0 += BK) {
    float4 av = aok ? ld4(Ap + k0) : float4{0.f, 0.f, 0.f, 0.f};
    float4 bv = bok ? ld4(Bp + k0) : float4{0.f, 0.f, 0.f, 0.f};
    __syncthreads();
    As[lk][lr] = av.x; As[lk + 1][lr] = av.y; As[lk + 2][lr] = av.z; As[lk + 3][lr] = av.w;
    Bs[lk][lr] = bv.x; Bs[lk + 1][lr] = bv.y; Bs[lk + 2][lr] = bv.z; Bs[lk + 3][lr] = bv.w;
    __syncthreads();
#pragma unroll
    for (int kk = 0; kk < BK; kk++) {
      float4 a = *(const float4*)&As[kk][r0];
      float4 b = *(const float4*)&Bs[kk][c0];
      float a4[4] = {a.x, a.y, a.z, a.w};
      float b4[4] = {b.x, b.y, b.z, b.w};
#pragma unroll
      for (int i = 0; i < 4; i++)
#pragma unroll
        for (int j = 0; j < 4; j++) acc[i][j] += a4[i] * b4[j];
    }
  }
#pragma unroll
  for (int i = 0; i < 4; i++) {
    int row = bm + r0 + i;
    if (row >= M) continue;
#pragma unroll
    for (int j = 0; j < 4; j++) {
      int col = bn + c0 + j;
      if (col >= N) continue;
      float v = acc[i][j];
      if (BIAS) v += bias[col];
      if (ACT == 1) v = (v > 20.0f) ? v : log1pf(expf(v));  // softplus
      if (RESID) v += resid[(size_t)row * ldc + col];
      C[(size_t)row * ldc + col] = v;
    }
  }
}

// ---------------- depthwise causal conv (K=4) + bias + SiLU ----------------
// reads xb = xz[:, 0:1536] (row stride 3072), writes u (row stride 1536)
__global__ __launch_bounds__(192) void conv_silu_kernel(const float* __restrict__ xz,
                                                        const float* __restrict__ cw,
                                                        const float* __restrict__ cb,
                                                        float* __restrict__ u) {
  int d4 = blockIdx.x * 192 + threadIdx.x;  // 0..383
  int m = blockIdx.y;                       // b*2048 + t
  int t = m & (LL - 1);
  int d = d4 << 2;
  float4 w0 = ld4(cw + d * 4);       // channel d taps 0..3
  float4 w1 = ld4(cw + d * 4 + 4);   // channel d+1
  float4 w2 = ld4(cw + d * 4 + 8);
  float4 w3 = ld4(cw + d * 4 + 12);
  float4 acc = {cb[d], cb[d + 1], cb[d + 2], cb[d + 3]};
  if (t >= 3) {
    float4 xv = ld4(xz + (size_t)(m - 3) * 3072 + d);
    acc.x += xv.x * w0.x; acc.y += xv.y * w1.x; acc.z += xv.z * w2.x; acc.w += xv.w * w3.x;
  }
  if (t >= 2) {
    float4 xv = ld4(xz + (size_t)(m - 2) * 3072 + d);
    acc.x += xv.x * w0.y; acc.y += xv.y * w1.y; acc.z += xv.z * w2.y; acc.w += xv.w * w3.y;
  }
  if (t >= 1) {
    float4 xv = ld4(xz + (size_t)(m - 1) * 3072 + d);
    acc.x += xv.x * w0.z; acc.y += xv.y * w1.z; acc.z += xv.z * w2.z; acc.w += xv.w * w3.z;
  }
  {
    float4 xv = ld4(xz + (size_t)m * 3072 + d);
    acc.x += xv.x * w0.w; acc.y += xv.y * w1.w; acc.z += xv.z * w2.w; acc.w += xv.w * w3.w;
  }
  float4 o;
  o.x = acc.x / (1.0f + __expf(-acc.x));
  o.y = acc.y / (1.0f + __expf(-acc.y));
  o.z = acc.z / (1.0f + __expf(-acc.z));
  o.w = acc.w / (1.0f + __expf(-acc.w));
  *(float4*)(u + (size_t)m * DI + d) = o;
}

// ---------------- selective scan (one thread per (b,d)) ----------------
// folds +u*D_skip and *silu(z) into the epilogue; writes gated y into yg
// (yg points at xz col 0..1535 region, row stride 3072)
__global__ __launch_bounds__(256) void scan_kernel(const float* __restrict__ delta,
                                                   const float* __restrict__ u,
                                                   const float* __restrict__ bc,
                                                   const float* xzbuf,
                                                   const float* __restrict__ A_log,
                                                   const float* __restrict__ D_skip,
                                                   float* yg) {
  int b = blockIdx.x / 6;
  int d = (blockIdx.x % 6) * 256 + threadIdx.x;
  float Acoef[NS];
#pragma unroll
  for (int n = 0; n < NS; n++) Acoef[n] = -__expf(A_log[d * NS + n] * 1.0f);
  float Dsk = D_skip[d];
  float h[NS];
#pragma unroll
  for (int n = 0; n < NS; n++) h[n] = 0.f;
  __shared__ float sBC[64][32];
  const float* bcb = bc + (size_t)b * LL * 32;
  for (int t0 = 0; t0 < LL; t0 += 64) {
    __syncthreads();
    for (int i = threadIdx.x; i < 64 * 32; i += 256) sBC[i >> 5][i & 31] = bcb[t0 * 32 + i];
    __syncthreads();
    for (int tt = 0; tt < 64; tt++) {
      int m = b * LL + t0 + tt;
      size_t off = (size_t)m * DI + d;
      float dl = delta[off];
      float ut = u[off];
      float yt = 0.f;
#pragma unroll
      for (int n = 0; n < NS; n++) {
        float dA = __expf(dl * Acoef[n]);
        h[n] = dA * h[n] + (dl * sBC[tt][n]) * ut;
        yt += h[n] * sBC[tt][16 + n];
      }
      float zv = xzbuf[(size_t)m * 3072 + DI + d];
      float sz = zv / (1.0f + __expf(-zv));
      yg[(size_t)m * 3072 + d] = (yt + ut * Dsk) * sz;
    }
  }
}

extern "C" void kernel_launch(void* const* d_in, const int* in_sizes, int n_in,
                              void* d_out, int out_size, void* d_ws, size_t ws_size,
                              hipStream_t stream) {
  const float* x = (const float*)d_in[0];
  const float* norm_w = (const float*)d_in[1];
  const float* in_proj_w = (const float*)d_in[2];
  const float* conv_w = (const float*)d_in[3];
  const float* conv_b = (const float*)d_in[4];
  const float* x_proj_w = (const float*)d_in[5];
  const float* dt_proj_w = (const float*)d_in[6];
  const float* dt_proj_b = (const float*)d_in[7];
  const float* A_log = (const float*)d_in[8];
  const float* D_skip = (const float*)d_in[9];
  const float* out_proj_w = (const float*)d_in[10];
  float* out = (float*)d_out;

  float* ws = (float*)d_ws;
  float* xn = ws;                   // 4096*768
  float* xz = xn + 3145728;         // 4096*3072
  float* u = xz + 12582912;         // 4096*1536
  float* delta = u + 6291456;       // 4096*1536
  float* bcb = delta + 6291456;     // 4096*32

  rmsnorm_kernel<<<4096, 256, 0, stream>>>(x, norm_w, xn);

  // xz = xn @ in_proj_w^T
  gemm_nt<0, false, false><<<dim3(48, 64), 256, 0, stream>>>(
      xn, in_proj_w, nullptr, nullptr, xz, MROWS, 3072, DM, DM, DM, 3072);

  // u = silu(causal_conv(xb) + conv_b)
  conv_silu_kernel<<<dim3(2, 4096), 192, 0, stream>>>(xz, conv_w, conv_b, u);

  // bc = u @ x_proj_w^T
  gemm_nt<0, false, false><<<dim3(1, 64), 256, 0, stream>>>(
      u, x_proj_w, nullptr, nullptr, bcb, MROWS, 32, DI, DI, DI, 32);

  // delta = softplus(u @ dt_proj_w^T + dt_proj_b)
  gemm_nt<1, true, false><<<dim3(24, 64), 256, 0, stream>>>(
      u, dt_proj_w, dt_proj_b, nullptr, delta, MROWS, DI, DI, DI, DI, DI);

  // selective scan + D_skip + silu(z) gating; gated y overwrites xb half of xz
  scan_kernel<<<12, 256, 0, stream>>>(delta, u, bcb, xz, A_log, D_skip, xz);

  // out = yg @ out_proj_w^T + x
  gemm_nt<0, false, true><<<dim3(12, 64), 256, 0, stream>>>(
      xz, out_proj_w, nullptr, x, out, MROWS, DM, DI, 3072, DI, DM);
}

// Round 2
// 904.117 us; speedup vs baseline: 2.1196x; 2.1196x over previous
//
#include <hip/hip_runtime.h>
#include <math.h>

#define DM 768
#define DI 1536
#define NS 16
#define LL 2048
#define MROWS 4096
#define CH 64
#define NC 32

__device__ __forceinline__ float4 ld4(const float* p) { return *(const float4*)p; }

// ---------------- RMSNorm ----------------
__global__ __launch_bounds__(256) void rmsnorm_kernel(const float* __restrict__ x,
                                                      const float* __restrict__ w,
                                                      float* __restrict__ xn) {
  int row = blockIdx.x;
  const float* xr = x + (size_t)row * DM;
  float* xo = xn + (size_t)row * DM;
  int tid = threadIdx.x;
  float v0 = xr[tid], v1 = xr[tid + 256], v2 = xr[tid + 512];
  float ss = v0 * v0 + v1 * v1 + v2 * v2;
#pragma unroll
  for (int o = 32; o > 0; o >>= 1) ss += __shfl_xor(ss, o, 64);
  __shared__ float red[4];
  if ((tid & 63) == 0) red[tid >> 6] = ss;
  __syncthreads();
  float tot = red[0] + red[1] + red[2] + red[3];
  float sc = rsqrtf(tot * (1.0f / 768.0f) + 1.1920928955078125e-07f);
  xo[tid] = v0 * sc * w[tid];
  xo[tid + 256] = v1 * sc * w[tid + 256];
  xo[tid + 512] = v2 * sc * w[tid + 512];
}

// ---------------- Generic fp32 NT-GEMM: C = act(A@B^T + bias) (+resid) ----------------
template <int ACT, bool BIAS, bool RESID>
__global__ __launch_bounds__(256) void gemm_nt(const float* __restrict__ A,
                                               const float* __restrict__ Bw,
                                               const float* __restrict__ bias,
                                               const float* __restrict__ resid,
                                               float* __restrict__ C, int M, int N,
                                               int K, int lda, int ldb, int ldc) {
  constexpr int BK = 16;
  __shared__ float As[BK][68];
  __shared__ float Bs[BK][68];
  int tid = threadIdx.x;
  int bm = blockIdx.y * 64, bn = blockIdx.x * 64;
  int lr = tid >> 2;
  int lk = (tid & 3) << 2;
  int r0 = (tid >> 4) << 2;
  int c0 = (tid & 15) << 2;
  float acc[4][4] = {};
  const float* Ap = A + (size_t)(bm + lr) * lda + lk;
  const float* Bp = Bw + (size_t)(bn + lr) * ldb + lk;
  bool aok = (bm + lr) < M;
  bool bok = (bn + lr) < N;
  for (int k0 = 0; k0 < K; k0 += BK) {
    float4 av = aok ? ld4(Ap + k0) : float4{0.f, 0.f, 0.f, 0.f};
    float4 bv = bok ? ld4(Bp + k0) : float4{0.f, 0.f, 0.f, 0.f};
    __syncthreads();
    As[lk][lr] = av.x; As[lk + 1][lr] = av.y; As[lk + 2][lr] = av.z; As[lk + 3][lr] = av.w;
    Bs[lk][lr] = bv.x; Bs[lk + 1][lr] = bv.y; Bs[lk + 2][lr] = bv.z; Bs[lk + 3][lr] = bv.w;
    __syncthreads();
#pragma unroll
    for (int kk = 0; kk < BK; kk++) {
      float4 a = *(const float4*)&As[kk][r0];
      float4 b = *(const float4*)&Bs[kk][c0];
      float a4[4] = {a.x, a.y, a.z, a.w};
      float b4[4] = {b.x, b.y, b.z, b.w};
#pragma unroll
      for (int i = 0; i < 4; i++)
#pragma unroll
        for (int j = 0; j < 4; j++) acc[i][j] += a4[i] * b4[j];
    }
  }
#pragma unroll
  for (int i = 0; i < 4; i++) {
    int row = bm + r0 + i;
    if (row >= M) continue;
#pragma unroll
    for (int j = 0; j < 4; j++) {
      int col = bn + c0 + j;
      if (col >= N) continue;
      float v = acc[i][j];
      if (BIAS) v += bias[col];
      if (ACT == 1) v = (v > 20.0f) ? v : log1pf(expf(v));
      if (RESID) v += resid[(size_t)row * ldc + col];
      C[(size_t)row * ldc + col] = v;
    }
  }
}

// ---------------- depthwise causal conv (K=4) + bias + SiLU ----------------
__global__ __launch_bounds__(192) void conv_silu_kernel(const float* __restrict__ xz,
                                                        const float* __restrict__ cw,
                                                        const float* __restrict__ cb,
                                                        float* __restrict__ u) {
  int d4 = blockIdx.x * 192 + threadIdx.x;
  int m = blockIdx.y;
  int t = m & (LL - 1);
  int d = d4 << 2;
  float4 w0 = ld4(cw + d * 4);
  float4 w1 = ld4(cw + d * 4 + 4);
  float4 w2 = ld4(cw + d * 4 + 8);
  float4 w3 = ld4(cw + d * 4 + 12);
  float4 acc = {cb[d], cb[d + 1], cb[d + 2], cb[d + 3]};
  if (t >= 3) {
    float4 xv = ld4(xz + (size_t)(m - 3) * 3072 + d);
    acc.x += xv.x * w0.x; acc.y += xv.y * w1.x; acc.z += xv.z * w2.x; acc.w += xv.w * w3.x;
  }
  if (t >= 2) {
    float4 xv = ld4(xz + (size_t)(m - 2) * 3072 + d);
    acc.x += xv.x * w0.y; acc.y += xv.y * w1.y; acc.z += xv.z * w2.y; acc.w += xv.w * w3.y;
  }
  if (t >= 1) {
    float4 xv = ld4(xz + (size_t)(m - 1) * 3072 + d);
    acc.x += xv.x * w0.z; acc.y += xv.y * w1.z; acc.z += xv.z * w2.z; acc.w += xv.w * w3.z;
  }
  {
    float4 xv = ld4(xz + (size_t)m * 3072 + d);
    acc.x += xv.x * w0.w; acc.y += xv.y * w1.w; acc.z += xv.z * w2.w; acc.w += xv.w * w3.w;
  }
  float4 o;
  o.x = acc.x / (1.0f + __expf(-acc.x));
  o.y = acc.y / (1.0f + __expf(-acc.y));
  o.z = acc.z / (1.0f + __expf(-acc.z));
  o.w = acc.w / (1.0f + __expf(-acc.w));
  *(float4*)(u + (size_t)m * DI + d) = o;
}

// ---------------- chunked selective scan ----------------
// pass1: per (b,d,chunk) compute P[n] = prod dA, S[n] = local scan from h=0
__global__ __launch_bounds__(256) void scan_pass1(const float* __restrict__ delta,
                                                  const float* __restrict__ u,
                                                  const float* __restrict__ bc,
                                                  const float* __restrict__ A_log,
                                                  float* __restrict__ chunkP,
                                                  float* __restrict__ chunkS) {
  int d = blockIdx.x * 256 + threadIdx.x;
  int c = blockIdx.y;
  int b = blockIdx.z;
  float Acoef[NS];
#pragma unroll
  for (int n = 0; n < NS; n++) Acoef[n] = -__expf(A_log[d * NS + n]);
  __shared__ float sB[CH][NS];
  const float* bcb = bc + (size_t)(b * LL + c * CH) * 32;
  for (int i = threadIdx.x; i < CH * NS; i += 256) sB[i >> 4][i & 15] = bcb[(i >> 4) * 32 + (i & 15)];
  __syncthreads();
  float P[NS], S[NS];
#pragma unroll
  for (int n = 0; n < NS; n++) { P[n] = 1.f; S[n] = 0.f; }
  int m0 = b * LL + c * CH;
  for (int tt = 0; tt < CH; tt++) {
    size_t off = (size_t)(m0 + tt) * DI + d;
    float dl = delta[off];
    float ut = u[off];
    float dlu = dl * ut;
#pragma unroll
    for (int n = 0; n < NS; n++) {
      float dA = __expf(dl * Acoef[n]);
      S[n] = dA * S[n] + dlu * sB[tt][n];
      P[n] *= dA;
    }
  }
  size_t base = ((size_t)(b * NC + c) * NS) * DI + d;
#pragma unroll
  for (int n = 0; n < NS; n++) {
    chunkP[base + (size_t)n * DI] = P[n];
    chunkS[base + (size_t)n * DI] = S[n];
  }
}

// pass2: per (b,d,n), combine 32 chunks; chunkS[c] is rewritten to h_in of chunk c
__global__ __launch_bounds__(256) void scan_pass2(const float* __restrict__ chunkP,
                                                  float* __restrict__ chunkS) {
  int id = blockIdx.x * 256 + threadIdx.x;  // < 2*16*1536
  int d = id % DI;
  int n = (id / DI) % NS;
  int b = id / (DI * NS);
  float h = 0.f;
  for (int c = 0; c < NC; c++) {
    size_t idx = ((size_t)(b * NC + c) * NS + n) * DI + d;
    float p = chunkP[idx];
    float s = chunkS[idx];
    chunkS[idx] = h;
    h = p * h + s;
  }
}

// pass3: re-run chunk from h_in, emit y; fold D_skip + silu(z); write into xz's xb half
__global__ __launch_bounds__(256) void scan_pass3(const float* __restrict__ delta,
                                                  const float* __restrict__ u,
                                                  const float* __restrict__ bc,
                                                  const float* __restrict__ hIn,
                                                  const float* __restrict__ A_log,
                                                  const float* __restrict__ D_skip,
                                                  const float* __restrict__ xzbuf,
                                                  float* __restrict__ yg) {
  int d = blockIdx.x * 256 + threadIdx.x;
  int c = blockIdx.y;
  int b = blockIdx.z;
  float Acoef[NS];
#pragma unroll
  for (int n = 0; n < NS; n++) Acoef[n] = -__expf(A_log[d * NS + n]);
  float Dsk = D_skip[d];
  __shared__ float sBC[CH][32];
  const float* bcb = bc + (size_t)(b * LL + c * CH) * 32;
  for (int i = threadIdx.x; i < CH * 32; i += 256) sBC[i >> 5][i & 31] = bcb[i];
  __syncthreads();
  float h[NS];
  size_t base = ((size_t)(b * NC + c) * NS) * DI + d;
#pragma unroll
  for (int n = 0; n < NS; n++) h[n] = hIn[base + (size_t)n * DI];
  int m0 = b * LL + c * CH;
  for (int tt = 0; tt < CH; tt++) {
    size_t m = (size_t)(m0 + tt);
    size_t off = m * DI + d;
    float dl = delta[off];
    float ut = u[off];
    float dlu = dl * ut;
    float yt = 0.f;
#pragma unroll
    for (int n = 0; n < NS; n++) {
      float dA = __expf(dl * Acoef[n]);
      h[n] = dA * h[n] + dlu * sBC[tt][n];
      yt += h[n] * sBC[tt][16 + n];
    }
    float zv = xzbuf[m * 3072 + DI + d];
    float sz = zv / (1.0f + __expf(-zv));
    yg[m * 3072 + d] = (yt + ut * Dsk) * sz;
  }
}

extern "C" void kernel_launch(void* const* d_in, const int* in_sizes, int n_in,
                              void* d_out, int out_size, void* d_ws, size_t ws_size,
                              hipStream_t stream) {
  const float* x = (const float*)d_in[0];
  const float* norm_w = (const float*)d_in[1];
  const float* in_proj_w = (const float*)d_in[2];
  const float* conv_w = (const float*)d_in[3];
  const float* conv_b = (const float*)d_in[4];
  const float* x_proj_w = (const float*)d_in[5];
  const float* dt_proj_w = (const float*)d_in[6];
  const float* dt_proj_b = (const float*)d_in[7];
  const float* A_log = (const float*)d_in[8];
  const float* D_skip = (const float*)d_in[9];
  const float* out_proj_w = (const float*)d_in[10];
  float* out = (float*)d_out;

  float* ws = (float*)d_ws;
  float* xn = ws;                   // 4096*768 = 3,145,728 floats
  float* xz = xn + 3145728;         // 4096*3072
  float* u = xz + 12582912;         // 4096*1536
  float* delta = u + 6291456;       // 4096*1536
  float* bcb = delta + 6291456;     // 4096*32
  // after in_proj, xn is dead; chunkP+chunkS (2 * 2*32*16*1536 = 3,145,728 floats) reuse it
  float* chunkP = xn;
  float* chunkS = xn + 1572864;

  rmsnorm_kernel<<<4096, 256, 0, stream>>>(x, norm_w, xn);

  gemm_nt<0, false, false><<<dim3(48, 64), 256, 0, stream>>>(
      xn, in_proj_w, nullptr, nullptr, xz, MROWS, 3072, DM, DM, DM, 3072);

  conv_silu_kernel<<<dim3(2, 4096), 192, 0, stream>>>(xz, conv_w, conv_b, u);

  gemm_nt<0, false, false><<<dim3(1, 64), 256, 0, stream>>>(
      u, x_proj_w, nullptr, nullptr, bcb, MROWS, 32, DI, DI, DI, 32);

  gemm_nt<1, true, false><<<dim3(24, 64), 256, 0, stream>>>(
      u, dt_proj_w, dt_proj_b, nullptr, delta, MROWS, DI, DI, DI, DI, DI);

  scan_pass1<<<dim3(6, NC, 2), 256, 0, stream>>>(delta, u, bcb, A_log, chunkP, chunkS);
  scan_pass2<<<192, 256, 0, stream>>>(chunkP, chunkS);
  scan_pass3<<<dim3(6, NC, 2), 256, 0, stream>>>(delta, u, bcb, chunkS, A_log, D_skip, xz, xz);

  gemm_nt<0, false, true><<<dim3(12, 64), 256, 0, stream>>>(
      xz, out_proj_w, nullptr, x, out, MROWS, DM, DI, 3072, DI, DM);
}

// Round 4
// 306.245 us; speedup vs baseline: 6.2576x; 2.9523x over previous
//
#include <hip/hip_runtime.h>
#include <math.h>

#define DM 768
#define DI 1536
#define NS 16
#define LL 2048
#define MROWS 4096
#define CH 64
#define NC 32

using bf16x8 = __attribute__((ext_vector_type(8))) short;
using f32x4 = __attribute__((ext_vector_type(4))) float;

__device__ __forceinline__ float4 ld4(const float* p) { return *(const float4*)p; }

__device__ __forceinline__ unsigned short f2bf(float f) {
  unsigned int u = __float_as_uint(f);
  u += 0x7fff + ((u >> 16) & 1);  // RNE
  return (unsigned short)(u >> 16);
}
__device__ __forceinline__ float b2f(unsigned short s) {
  return __uint_as_float(((unsigned int)s) << 16);
}

__device__ __forceinline__ void gload16(const void* g, void* l) {
  __builtin_amdgcn_global_load_lds((const __attribute__((address_space(1))) void*)g,
                                   (__attribute__((address_space(3))) void*)l, 16, 0, 0);
}

// ---------------- fp32 -> bf16 converters ----------------
__global__ __launch_bounds__(256) void cvt4(const float* __restrict__ src,
                                            unsigned short* __restrict__ dst, int n4) {
  int i = blockIdx.x * 256 + threadIdx.x;
  if (i >= n4) return;
  float4 v = ld4(src + (size_t)i * 4);
  ushort4 o = {f2bf(v.x), f2bf(v.y), f2bf(v.z), f2bf(v.w)};
  *(ushort4*)(dst + (size_t)i * 4) = o;
}

// concat [dt_proj_w (1536xK); x_proj_w (32xK); zeros (96xK)] -> 1664xK bf16
__global__ __launch_bounds__(256) void cvt_cat(const float* __restrict__ dtw,
                                               const float* __restrict__ xpw,
                                               unsigned short* __restrict__ dst) {
  int i = blockIdx.x * 256 + threadIdx.x;  // over 1664*1536/4
  if (i >= 1664 * 384) return;
  int row = i / 384;
  int col = (i % 384) * 4;
  ushort4 o = {0, 0, 0, 0};
  if (row < 1536) {
    float4 v = ld4(dtw + (size_t)row * DI + col);
    o = {f2bf(v.x), f2bf(v.y), f2bf(v.z), f2bf(v.w)};
  } else if (row < 1568) {
    float4 v = ld4(xpw + (size_t)(row - 1536) * DI + col);
    o = {f2bf(v.x), f2bf(v.y), f2bf(v.z), f2bf(v.w)};
  }
  *(ushort4*)(dst + (size_t)i * 4) = o;
}

// ---------------- RMSNorm -> bf16 ----------------
__global__ __launch_bounds__(256) void rmsnorm_kernel(const float* __restrict__ x,
                                                      const float* __restrict__ w,
                                                      unsigned short* __restrict__ xn) {
  int row = blockIdx.x;
  const float* xr = x + (size_t)row * DM;
  unsigned short* xo = xn + (size_t)row * DM;
  int tid = threadIdx.x;
  float v0 = xr[tid], v1 = xr[tid + 256], v2 = xr[tid + 512];
  float ss = v0 * v0 + v1 * v1 + v2 * v2;
#pragma unroll
  for (int o = 32; o > 0; o >>= 1) ss += __shfl_xor(ss, o, 64);
  __shared__ float red[4];
  if ((tid & 63) == 0) red[tid >> 6] = ss;
  __syncthreads();
  float tot = red[0] + red[1] + red[2] + red[3];
  float sc = rsqrtf(tot * (1.0f / 768.0f) + 1.1920928955078125e-07f);
  xo[tid] = f2bf(v0 * sc * w[tid]);
  xo[tid + 256] = f2bf(v1 * sc * w[tid + 256]);
  xo[tid + 512] = f2bf(v2 * sc * w[tid + 512]);
}

// ---------------- bf16 MFMA NT-GEMM: C = A(MxK) @ Bw(NxK)^T ----------------
// 128x128 tile, BK=64, 4 waves (2x2), each wave 64x64 via 4x4 mfma_16x16x32 frags.
// EPI 0: split store xb/z (in_proj). EPI 1: softplus+bias -> delta, cols 1536..1567 -> bc.
// EPI 2: + resid -> out.
template <int EPI>
__global__ __launch_bounds__(256) void mfma_gemm(const unsigned short* __restrict__ A,
                                                 const unsigned short* __restrict__ Bw,
                                                 const float* __restrict__ bias,
                                                 const float* __restrict__ resid,
                                                 float* __restrict__ o0,
                                                 float* __restrict__ o1, int K) {
  __shared__ unsigned short As[128 * 64];
  __shared__ unsigned short Bs[128 * 64];
  int tid = threadIdx.x;
  int lane = tid & 63, w = tid >> 6;
  int wr = w >> 1, wc = w & 1;
  int bm = blockIdx.y * 128, bn = blockIdx.x * 128;

  f32x4 acc[4][4];
#pragma unroll
  for (int i = 0; i < 4; i++)
#pragma unroll
    for (int j = 0; j < 4; j++) acc[i][j] = (f32x4){0.f, 0.f, 0.f, 0.f};

  const unsigned short* Ab = A + (size_t)bm * K;
  const unsigned short* Bb = Bw + (size_t)bn * K;
  int lrow = lane >> 3;        // 0..7 row within 8-row chunk
  int kof = (lane & 7) * 8;    // bf16 elements

  for (int k0 = 0; k0 < K; k0 += 64) {
    __syncthreads();  // previous tile's readers done
#pragma unroll
    for (int q = 0; q < 4; q++) {
      int ch = w * 4 + q;            // 0..15
      int row = ch * 8 + lrow;       // 0..127
      gload16(Ab + (size_t)row * K + k0 + kof, &As[ch * 512]);
      gload16(Bb + (size_t)row * K + k0 + kof, &Bs[ch * 512]);
    }
    __syncthreads();  // compiler drains vmcnt before barrier
#pragma unroll
    for (int kk = 0; kk < 2; kk++) {
      bf16x8 af[4], bfr[4];
#pragma unroll
      for (int i = 0; i < 4; i++) {
        int arow = wr * 64 + i * 16 + (lane & 15);
        af[i] = *(const bf16x8*)&As[arow * 64 + kk * 32 + (lane >> 4) * 8];
        int brow = wc * 64 + i * 16 + (lane & 15);
        bfr[i] = *(const bf16x8*)&Bs[brow * 64 + kk * 32 + (lane >> 4) * 8];
      }
#pragma unroll
      for (int i = 0; i < 4; i++)
#pragma unroll
        for (int j = 0; j < 4; j++)
          acc[i][j] = __builtin_amdgcn_mfma_f32_16x16x32_bf16(af[i], bfr[j], acc[i][j], 0, 0, 0);
    }
  }

  // epilogue: C/D layout col=lane&15, row=(lane>>4)*4+r  [m89-verified]
#pragma unroll
  for (int i = 0; i < 4; i++) {
#pragma unroll
    for (int j = 0; j < 4; j++) {
      int row0 = bm + wr * 64 + i * 16 + (lane >> 4) * 4;
      int col = bn + wc * 64 + j * 16 + (lane & 15);
#pragma unroll
      for (int r = 0; r < 4; r++) {
        float v = acc[i][j][r];
        int row = row0 + r;
        if (EPI == 0) {
          if (col < DI) o0[(size_t)row * DI + col] = v;
          else o1[(size_t)row * DI + col - DI] = v;
        } else if (EPI == 1) {
          if (col < DI) {
            v += bias[col];
            v = (v > 20.0f) ? v : log1pf(expf(v));
            o0[(size_t)row * DI + col] = v;
          } else if (col < DI + 2 * NS) {
            o1[(size_t)row * 32 + col - DI] = v;
          }
        } else {
          o0[(size_t)row * DM + col] = v + resid[(size_t)row * DM + col];
        }
      }
    }
  }
}

// ---------------- depthwise causal conv (K=4) + bias + SiLU -> bf16 ----------------
__global__ __launch_bounds__(192) void conv_silu_kernel(const float* __restrict__ xb,
                                                        const float* __restrict__ cw,
                                                        const float* __restrict__ cb,
                                                        unsigned short* __restrict__ u) {
  int d = (blockIdx.x * 192 + threadIdx.x) << 2;  // 0..1532
  int m = blockIdx.y;
  int t = m & (LL - 1);
  float4 w0 = ld4(cw + d * 4);
  float4 w1 = ld4(cw + d * 4 + 4);
  float4 w2 = ld4(cw + d * 4 + 8);
  float4 w3 = ld4(cw + d * 4 + 12);
  float4 acc = {cb[d], cb[d + 1], cb[d + 2], cb[d + 3]};
  if (t >= 3) {
    float4 xv = ld4(xb + (size_t)(m - 3) * DI + d);
    acc.x += xv.x * w0.x; acc.y += xv.y * w1.x; acc.z += xv.z * w2.x; acc.w += xv.w * w3.x;
  }
  if (t >= 2) {
    float4 xv = ld4(xb + (size_t)(m - 2) * DI + d);
    acc.x += xv.x * w0.y; acc.y += xv.y * w1.y; acc.z += xv.z * w2.y; acc.w += xv.w * w3.y;
  }
  if (t >= 1) {
    float4 xv = ld4(xb + (size_t)(m - 1) * DI + d);
    acc.x += xv.x * w0.z; acc.y += xv.y * w1.z; acc.z += xv.z * w2.z; acc.w += xv.w * w3.z;
  }
  {
    float4 xv = ld4(xb + (size_t)m * DI + d);
    acc.x += xv.x * w0.w; acc.y += xv.y * w1.w; acc.z += xv.z * w2.w; acc.w += xv.w * w3.w;
  }
  ushort4 o = {f2bf(acc.x / (1.0f + __expf(-acc.x))), f2bf(acc.y / (1.0f + __expf(-acc.y))),
               f2bf(acc.z / (1.0f + __expf(-acc.z))), f2bf(acc.w / (1.0f + __expf(-acc.w)))};
  *(ushort4*)(u + (size_t)m * DI + d) = o;
}

// ---------------- chunked selective scan ----------------
__global__ __launch_bounds__(256) void scan_pass1(const float* __restrict__ delta,
                                                  const unsigned short* __restrict__ u,
                                                  const float* __restrict__ bc,
                                                  const float* __restrict__ A_log,
                                                  float* __restrict__ chunkP,
                                                  float* __restrict__ chunkS) {
  int d = blockIdx.x * 256 + threadIdx.x;
  int c = blockIdx.y;
  int b = blockIdx.z;
  float Acoef[NS];
#pragma unroll
  for (int n = 0; n < NS; n++) Acoef[n] = -__expf(A_log[d * NS + n]);
  __shared__ float sB[CH][NS];
  const float* bcb = bc + (size_t)(b * LL + c * CH) * 32;
  for (int i = threadIdx.x; i < CH * NS; i += 256) sB[i >> 4][i & 15] = bcb[(i >> 4) * 32 + (i & 15)];
  __syncthreads();
  float P[NS], S[NS];
#pragma unroll
  for (int n = 0; n < NS; n++) { P[n] = 1.f; S[n] = 0.f; }
  int m0 = b * LL + c * CH;
  for (int tt = 0; tt < CH; tt++) {
    size_t off = (size_t)(m0 + tt) * DI + d;
    float dl = delta[off];
    float ut = b2f(u[off]);
    float dlu = dl * ut;
#pragma unroll
    for (int n = 0; n < NS; n++) {
      float dA = __expf(dl * Acoef[n]);
      S[n] = dA * S[n] + dlu * sB[tt][n];
      P[n] *= dA;
    }
  }
  size_t base = ((size_t)(b * NC + c) * NS) * DI + d;
#pragma unroll
  for (int n = 0; n < NS; n++) {
    chunkP[base + (size_t)n * DI] = P[n];
    chunkS[base + (size_t)n * DI] = S[n];
  }
}

__global__ __launch_bounds__(256) void scan_pass2(const float* __restrict__ chunkP,
                                                  float* __restrict__ chunkS) {
  int id = blockIdx.x * 256 + threadIdx.x;
  int d = id % DI;
  int n = (id / DI) % NS;
  int b = id / (DI * NS);
  float h = 0.f;
  for (int c = 0; c < NC; c++) {
    size_t idx = ((size_t)(b * NC + c) * NS + n) * DI + d;
    float p = chunkP[idx];
    float s = chunkS[idx];
    chunkS[idx] = h;
    h = p * h + s;
  }
}

__global__ __launch_bounds__(256) void scan_pass3(const float* __restrict__ delta,
                                                  const unsigned short* __restrict__ u,
                                                  const float* __restrict__ bc,
                                                  const float* __restrict__ hIn,
                                                  const float* __restrict__ A_log,
                                                  const float* __restrict__ D_skip,
                                                  const float* __restrict__ z,
                                                  unsigned short* __restrict__ yg) {
  int d = blockIdx.x * 256 + threadIdx.x;
  int c = blockIdx.y;
  int b = blockIdx.z;
  float Acoef[NS];
#pragma unroll
  for (int n = 0; n < NS; n++) Acoef[n] = -__expf(A_log[d * NS + n]);
  float Dsk = D_skip[d];
  __shared__ float sBC[CH][32];
  const float* bcb = bc + (size_t)(b * LL + c * CH) * 32;
  for (int i = threadIdx.x; i < CH * 32; i += 256) sBC[i >> 5][i & 31] = bcb[i];
  __syncthreads();
  float h[NS];
  size_t base = ((size_t)(b * NC + c) * NS) * DI + d;
#pragma unroll
  for (int n = 0; n < NS; n++) h[n] = hIn[base + (size_t)n * DI];
  int m0 = b * LL + c * CH;
  for (int tt = 0; tt < CH; tt++) {
    size_t m = (size_t)(m0 + tt);
    size_t off = m * DI + d;
    float dl = delta[off];
    float ut = b2f(u[off]);
    float dlu = dl * ut;
    float yt = 0.f;
#pragma unroll
    for (int n = 0; n < NS; n++) {
      float dA = __expf(dl * Acoef[n]);
      h[n] = dA * h[n] + dlu * sBC[tt][n];
      yt += h[n] * sBC[tt][16 + n];
    }
    float zv = z[m * DI + d];
    float sz = zv / (1.0f + __expf(-zv));
    yg[m * DI + d] = f2bf((yt + ut * Dsk) * sz);
  }
}

extern "C" void kernel_launch(void* const* d_in, const int* in_sizes, int n_in,
                              void* d_out, int out_size, void* d_ws, size_t ws_size,
                              hipStream_t stream) {
  const float* x = (const float*)d_in[0];
  const float* norm_w = (const float*)d_in[1];
  const float* in_proj_w = (const float*)d_in[2];
  const float* conv_w = (const float*)d_in[3];
  const float* conv_b = (const float*)d_in[4];
  const float* x_proj_w = (const float*)d_in[5];
  const float* dt_proj_w = (const float*)d_in[6];
  const float* dt_proj_b = (const float*)d_in[7];
  const float* A_log = (const float*)d_in[8];
  const float* D_skip = (const float*)d_in[9];
  const float* out_proj_w = (const float*)d_in[10];
  float* out = (float*)d_out;

  float* ws = (float*)d_ws;
  float* xb = ws;                                      // 4096*1536
  float* z = ws + 6291456;                             // 4096*1536
  unsigned short* u_bf = (unsigned short*)(ws + 12582912);   // 4096*1536 bf16
  float* delta = ws + 15728640;                        // 4096*1536
  unsigned short* ygbf = (unsigned short*)(ws + 22020096);   // 4096*1536 bf16
  unsigned short* wbf_in = (unsigned short*)(ws + 25165824); // 3072*768 bf16
  unsigned short* wbf_cat = (unsigned short*)(ws + 26345472);// 1664*1536 bf16
  unsigned short* wbf_out = (unsigned short*)(ws + 27623424);// 768*1536 bf16
  // xb is dead after conv -> reuse for chunk state
  float* chunkP = xb;
  float* chunkS = xb + 1572864;
  // d_out doubles as scratch before the final GEMM writes it
  unsigned short* xn_bf = (unsigned short*)d_out;      // 4096*768 bf16 = 1572864 floats
  float* bcb = (float*)d_out + 1572864;                // 4096*32

  cvt4<<<2304, 256, 0, stream>>>(in_proj_w, wbf_in, 589824);
  cvt_cat<<<2496, 256, 0, stream>>>(dt_proj_w, x_proj_w, wbf_cat);
  cvt4<<<1152, 256, 0, stream>>>(out_proj_w, wbf_out, 294912);

  rmsnorm_kernel<<<4096, 256, 0, stream>>>(x, norm_w, xn_bf);

  // xb|z = rmsnorm(x) @ in_proj_w^T   (M=4096, N=3072, K=768)
  mfma_gemm<0><<<dim3(24, 32), 256, 0, stream>>>(xn_bf, wbf_in, nullptr, nullptr, xb, z, DM);

  conv_silu_kernel<<<dim3(2, 4096), 192, 0, stream>>>(xb, conv_w, conv_b, u_bf);

  // delta|bc = u @ [dt_proj_w; x_proj_w]^T  (M=4096, N=1664, K=1536)
  mfma_gemm<1><<<dim3(13, 32), 256, 0, stream>>>(u_bf, wbf_cat, dt_proj_b, nullptr, delta, bcb, DI);

  scan_pass1<<<dim3(6, NC, 2), 256, 0, stream>>>(delta, u_bf, bcb, A_log, chunkP, chunkS);
  scan_pass2<<<192, 256, 0, stream>>>(chunkP, chunkS);
  scan_pass3<<<dim3(6, NC, 2), 256, 0, stream>>>(delta, u_bf, bcb, chunkS, A_log, D_skip, z, ygbf);

  // out = yg @ out_proj_w^T + x  (M=4096, N=768, K=1536)
  mfma_gemm<2><<<dim3(6, 32), 256, 0, stream>>>(ygbf, wbf_out, nullptr, x, out, nullptr, DI);
}